// Round 1
// baseline (689.919 us; speedup 1.0000x reference)
//
#include <hip/hip_runtime.h>

// CRF path score: out = -( sum_i logits[i, tags[i]] + sum_{i>0} T[tags[i-1], tags[i]] )
// S = 2,000,000 rows, NUM_TAGS = 50.
//
// R2 -> R3: gather -> STREAM. The per-row emission gather issues 64 distinct
// cache lines per wave instruction (lanes 800 B apart); the memory system sees
// ~2M isolated line requests from 256 CUs at once -> ~1 TB/s effective (kernel
// ~246 us). Instead, stream the ENTIRE logits array coalesced (uint4) into LDS
// tile-by-tile at full streaming BW (~6.3 TB/s) and do the 1-of-50 selection
// from LDS. 400 MB @ 6.3 TB/s (~65 us) beats ~250 MB @ ~1 TB/s (~246 us).
//
// Tile = 256 rows (51.2 KB) + trans (10 KB) + tags (1 KB) = ~62.3 KB LDS
//  -> 2 blocks/CU, 8 waves/CU, all 512 blocks resident (grid-stride over tiles).
// Loads are register-staged (13 independent dwordx4 per thread, clustered
// before the LDS writes) -> ~100 KB in flight per CU >> BW*latency (~9 KB).

#define NUM_TAGS 50
#define TILE 256
#define THREADS 256
#define VEC_PER_TILE ((TILE * NUM_TAGS) / 4)                        // 3200 uint4
#define LOADS_PER_THREAD ((VEC_PER_TILE + THREADS - 1) / THREADS)   // 13

__global__ __launch_bounds__(THREADS) void crf_score_kernel(
    const float* __restrict__ logits,
    const int*   __restrict__ tags,
    const float* __restrict__ trans,
    float* __restrict__ out,
    int n)
{
    __shared__ __align__(16) float s_log[TILE * NUM_TAGS];   // 51200 B
    __shared__ float s_trans[NUM_TAGS * NUM_TAGS];           // 10000 B
    __shared__ int   s_tags[TILE + 1];                       //  1028 B
    __shared__ float s_part[THREADS / 64];

    const int tid = threadIdx.x;

    // transitions table: 10 KB, staged once per block (L2-hot after first blocks)
    for (int i = tid; i < NUM_TAGS * NUM_TAGS; i += THREADS)
        s_trans[i] = trans[i];

    const int ntiles = (n + TILE - 1) / TILE;
    float acc = 0.0f;

    for (int tile = blockIdx.x; tile < ntiles; tile += gridDim.x) {
        const long long base = (long long)tile * TILE;
        const long long rem  = (long long)n - base;
        const int rows = (rem < TILE) ? (int)rem : TILE;
        const int nflt = rows * NUM_TAGS;
        const int nvec = nflt >> 2;   // rows*50 is divisible by 4 whenever rows is even

        // ---- issue phase: all global loads up front (independent, clustered) ----
        const uint4* g = (const uint4*)(logits + base * NUM_TAGS);  // 16B-aligned: 51200 | tile offset
        uint4 r[LOADS_PER_THREAD];
        #pragma unroll
        for (int k = 0; k < LOADS_PER_THREAD; ++k) {
            const int idx = tid + k * THREADS;
            if (idx < nvec) r[k] = g[idx];
        }
        int tg = 0;
        if (tid < rows) tg = tags[base + tid];          // coalesced
        int tgN = 0;
        if (tid == 0 && base + rows < n) tgN = tags[base + rows];  // boundary into next tile

        // ---- write phase: previous tile's consumers must be done first ----
        __syncthreads();
        #pragma unroll
        for (int k = 0; k < LOADS_PER_THREAD; ++k) {
            const int idx = tid + k * THREADS;
            if (idx < nvec) ((uint4*)s_log)[idx] = r[k];
        }
        // generic scalar tail (unused when rows is even; kept for safety)
        for (int idx = (nvec << 2) + tid; idx < nflt; idx += THREADS)
            s_log[idx] = logits[base * NUM_TAGS + idx];
        if (tid < rows) s_tags[tid] = tg;
        if (tid == 0)   s_tags[rows] = tgN;
        __syncthreads();

        // ---- select phase: 1 LDS read per row + transition lookup ----
        if (tid < rows) {
            const int t = s_tags[tid];
            float v = s_log[tid * NUM_TAGS + t];
            if (base + tid + 1 < n) {
                const int t2 = s_tags[tid + 1];
                v += s_trans[t * NUM_TAGS + t2];
            }
            acc += v;
        }
    }

    // ---- hierarchical reduce: wave shuffle -> LDS -> one atomic per block ----
    #pragma unroll
    for (int off = 32; off > 0; off >>= 1)
        acc += __shfl_down(acc, off, 64);

    const int lane = tid & 63;
    const int wid  = tid >> 6;
    if (lane == 0) s_part[wid] = acc;
    __syncthreads();

    if (wid == 0) {
        float v = (lane < THREADS / 64) ? s_part[lane] : 0.0f;
        #pragma unroll
        for (int off = 2; off > 0; off >>= 1)
            v += __shfl_down(v, off, 64);
        if (lane == 0)
            atomicAdd(out, -v);   // reference returns -(emit + trans)
    }
}

extern "C" void kernel_launch(void* const* d_in, const int* in_sizes, int n_in,
                              void* d_out, int out_size, void* d_ws, size_t ws_size,
                              hipStream_t stream) {
    const float* logits = (const float*)d_in[0];
    const int*   tags   = (const int*)d_in[1];
    const float* trans  = (const float*)d_in[2];
    float* out = (float*)d_out;
    const int n = in_sizes[1];  // SEQ_LEN

    // d_out is poisoned before every timed launch — zero it on-stream.
    hipMemsetAsync(out, 0, sizeof(float), stream);

    const int ntiles = (n + TILE - 1) / TILE;
    const int grid = (ntiles < 512) ? ntiles : 512;  // 62.3 KB LDS -> 2 blocks/CU -> all resident
    crf_score_kernel<<<grid, THREADS, 0, stream>>>(logits, tags, trans, out, n);
}

// Round 2
// 528.235 us; speedup vs baseline: 1.3061x; 1.3061x over previous
//
#include <hip/hip_runtime.h>
#include <stdint.h>

// CRF path score: out = -( sum_i logits[i, tags[i]] + sum_{i>0} T[tags[i-1], tags[i]] )
// S = 2,000,000 rows, NUM_TAGS = 50.
//
// R3 -> R4: kill the scratch round-trip. R3's uint4 r[13] staging array was
// spilled to scratch (evidence: WRITE_SIZE ~= 390 MB =~ sizeof(logits) of pure
// scratch writebacks, VGPR_Count=88 too small for 13 live uint4). Replace the
// global->reg->LDS path with __builtin_amdgcn_global_load_lds (direct
// global->LDS DMA, 16 B/lane, zero VGPRs, zero scratch). The compiler NEVER
// emits this on its own (guide Common-mistake #1).
//
// TILE=128 rows (25.6 KB), double-buffered: issue tile t+1's DMA right after
// the barrier, select tile t from the other buffer. The barrier's implicit
// s_waitcnt vmcnt(0) lands exactly before the consumer of the prefetched
// buffer. LDS = 2*25.6K + 10K trans + tags ~= 62 KB -> 2 blocks/CU,
// 8 waves/CU, ~50 KB of DMA in flight per CU (>> ~9 KB BW*latency product).
//
// HBM floor: 400 MB logits + 8 MB tags @ ~6.3 TB/s ~= 65 us.

#define NUM_TAGS 50
#define TILE 128
#define THREADS 256
#define WAVES (THREADS / 64)
#define TILE_FLOATS (TILE * NUM_TAGS)   // 6400 floats = 25600 B
#define TILE_VEC (TILE_FLOATS / 4)      // 1600 uint4

typedef __attribute__((address_space(3))) uint32_t lds_u32_t;
typedef __attribute__((address_space(1))) uint32_t g_u32_t;

// Direct global->LDS DMA: 64 lanes x 16 B = 1024 B per call per wave.
// LDS dest = wave-uniform base + lane*16 (hardware rule); global addr per-lane.
__device__ __forceinline__ void gload_lds16(const void* gp, void* lds_generic) {
    __builtin_amdgcn_global_load_lds(
        (const g_u32_t*)(uintptr_t)gp,
        (lds_u32_t*)(uint32_t)(uintptr_t)lds_generic,  // flat->AS3: low 32 bits = LDS offset
        16, 0, 0);
}

__global__ __launch_bounds__(THREADS) void crf_score_kernel(
    const float* __restrict__ logits,
    const int*   __restrict__ tags,
    const float* __restrict__ trans,
    float* __restrict__ out,
    int n)
{
    __shared__ __align__(16) float s_log[2][TILE_FLOATS];  // 2 x 25600 B
    __shared__ float s_trans[NUM_TAGS * NUM_TAGS];         // 10000 B
    __shared__ int   s_tags[2][TILE + 2];                  // 2 x 520 B
    __shared__ float s_part[WAVES];

    const int tid  = threadIdx.x;
    const int lane = tid & 63;
    const int wid  = tid >> 6;

    // transitions table: 10 KB, staged once per block (L2/L3-hot after first blocks)
    for (int i = tid; i < NUM_TAGS * NUM_TAGS; i += THREADS)
        s_trans[i] = trans[i];

    const int ntiles = (n + TILE - 1) / TILE;

    // Issue async loads for `tile` into buffer b. No registers touched for logits.
    auto stage = [&](long long tile, int b) {
        const long long base = tile * TILE;
        const long long rem  = (long long)n - base;
        const int rows = (rem < TILE) ? (int)rem : TILE;
        const int nflt = rows * NUM_TAGS;
        const int nchunks = nflt >> 8;  // 256 floats (1024 B) per wave-chunk
        const uint4* g = (const uint4*)(logits + base * NUM_TAGS);  // 16B-aligned: base*200 % 16 == 0
        for (int c = wid; c < nchunks; c += WAVES)
            gload_lds16(g + (c << 6) + lane, &s_log[b][c << 8]);
        // generic scalar tail (nflt % 256 floats); unused for TILE=128 full/half tiles
        for (int idx = (nchunks << 8) + tid; idx < nflt; idx += THREADS)
            s_log[b][idx] = logits[base * NUM_TAGS + idx];
        // tags for this tile + boundary tag into the next tile (tid == rows)
        if (tid <= rows && base + tid < n)
            s_tags[b][tid] = tags[base + tid];
    };

    float acc = 0.0f;
    long long t0 = blockIdx.x;
    if (t0 < ntiles) {
        int b = 0;
        stage(t0, 0);
        for (;;) {
            const long long t1 = t0 + gridDim.x;
            // Drains vmcnt(0)+lgkmcnt(0): buffer b's DMA complete; also guarantees
            // the select that previously read buffer b^1 is finished block-wide.
            __syncthreads();
            if (t1 < ntiles) stage(t1, b ^ 1);  // prefetch overlaps select below

            const long long base = t0 * TILE;
            const long long rem  = (long long)n - base;
            const int rows = (rem < TILE) ? (int)rem : TILE;
            if (tid < rows) {
                const int t = s_tags[b][tid];
                float v = s_log[b][tid * NUM_TAGS + t];
                if (base + tid + 1 < n)
                    v += s_trans[t * NUM_TAGS + s_tags[b][tid + 1]];
                acc += v;
            }

            if (t1 >= ntiles) break;
            t0 = t1;
            b ^= 1;
        }
    }

    // hierarchical reduce: wave shuffle -> LDS -> one atomic per block
    #pragma unroll
    for (int off = 32; off > 0; off >>= 1)
        acc += __shfl_down(acc, off, 64);

    if (lane == 0) s_part[wid] = acc;
    __syncthreads();

    if (wid == 0) {
        float v = (lane < WAVES) ? s_part[lane] : 0.0f;
        #pragma unroll
        for (int off = 2; off > 0; off >>= 1)
            v += __shfl_down(v, off, 64);
        if (lane == 0)
            atomicAdd(out, -v);  // reference returns -(emit + trans)
    }
}

extern "C" void kernel_launch(void* const* d_in, const int* in_sizes, int n_in,
                              void* d_out, int out_size, void* d_ws, size_t ws_size,
                              hipStream_t stream) {
    const float* logits = (const float*)d_in[0];
    const int*   tags   = (const int*)d_in[1];
    const float* trans  = (const float*)d_in[2];
    float* out = (float*)d_out;
    const int n = in_sizes[1];  // SEQ_LEN

    // d_out is poisoned before every timed launch — zero it on-stream.
    hipMemsetAsync(out, 0, sizeof(float), stream);

    const int ntiles = (n + TILE - 1) / TILE;
    const int grid = (ntiles < 512) ? ntiles : 512;  // 62 KB LDS -> 2 blocks/CU -> all resident
    crf_score_kernel<<<grid, THREADS, 0, stream>>>(logits, tags, trans, out, n);
}

// Round 3
// 523.897 us; speedup vs baseline: 1.3169x; 1.0083x over previous
//
#include <hip/hip_runtime.h>
#include <stdint.h>

// CRF path score: out = -( sum_i logits[i, tags[i]] + sum_{i>0} T[tags[i-1], tags[i]] )
// S = 2,000,000 rows, NUM_TAGS = 50. Memory-bound: must stream 400 MB of logits.
//
// R4 -> R5: kill every implicit vmcnt(0) in the main loop.
//  - R4's s_tags VGPR-load->ds_write forced a full vmcnt(0) INSIDE stage()
//    (ds_write waits on newest vmem op => drains the just-issued prefetch DMA).
//  - __syncthreads() itself drains vmcnt(0) before s_barrier (m97 lesson).
//  => R4 was issue -> full-drain -> select -> barrier, fully serialized, with
//     all blocks convoying (burst/stall duty cycle on HBM).
// New structure: ONE WAVE PER BLOCK, private double-buffered pipeline,
// counted s_waitcnt vmcnt(28) (T3/T4). Tags staged via DMA too (clamped so
// every tile is exactly 28 vmem ops -> constant immediate). No s_barrier
// anywhere. 2 blocks/CU (62.7 KB LDS) -> ~52 KB DMA in flight per CU.
// HBM floor: 400 MB logits + ~12 MB tags + 5 MB trans @ ~6.3 TB/s ~= 66 us.

#define NUM_TAGS 50
#define TILE 128                         // rows per tile
#define LOG_CHUNKS 25                    // 25 x (64 lanes x 16 B) = 25600 B = TILE*200
#define TAG_CHUNKS 3                     // 3 x (64 lanes x 4 B) = 192 ints (need 129)
#define OPS_PER_TILE (LOG_CHUNKS + TAG_CHUNKS)   // 28, constant for EVERY tile
#define GRID 512

typedef __attribute__((address_space(3))) uint32_t lds_u32_t;
typedef __attribute__((address_space(1))) uint32_t g_u32_t;

// Direct global->LDS DMA. Global address is per-lane; LDS dest is wave-uniform
// base (+ lane*size applied by HW). Conversion style verified correct in R4.
__device__ __forceinline__ void dma16(const void* gp, void* lds) {
    __builtin_amdgcn_global_load_lds((const g_u32_t*)(uintptr_t)gp,
        (lds_u32_t*)(uint32_t)(uintptr_t)lds, 16, 0, 0);
}
__device__ __forceinline__ void dma4(const void* gp, void* lds) {
    __builtin_amdgcn_global_load_lds((const g_u32_t*)(uintptr_t)gp,
        (lds_u32_t*)(uint32_t)(uintptr_t)lds, 4, 0, 0);
}

__global__ __launch_bounds__(64) void crf_score_kernel(
    const float* __restrict__ logits,
    const int*   __restrict__ tags,
    const float* __restrict__ trans,
    float* __restrict__ out,
    int n)
{
    __shared__ __align__(16) float s_log[2][TILE * NUM_TAGS];   // 2 x 25600 B
    __shared__ __align__(16) int   s_tag[2][TAG_CHUNKS * 64];   // 2 x 768 B
    __shared__ __align__(16) float s_trans[NUM_TAGS * NUM_TAGS];// 10000 B
    // total 62736 B -> 2 blocks/CU; single wave -> no barriers needed at all

    const int lane = threadIdx.x;            // 64 threads = exactly one wave
    const long long nn = n;

    // One-time transitions staging (vectorized VGPR round-trip is fine here;
    // these vmem ops are the oldest, so the first vmcnt(28) also covers them).
    {
        const uint4* t4 = (const uint4*)trans;        // 2500 floats = 625 uint4
        uint4* s4 = (uint4*)s_trans;
        for (int i = lane; i < (NUM_TAGS * NUM_TAGS) / 4; i += 64)
            s4[i] = t4[i];
    }

    const int ntiles = (int)((nn + TILE - 1) / TILE);
    const float* glim = logits + nn * NUM_TAGS;       // clamp limit (16B-aligned)
    const int* tlim = tags + nn;

    // Issue exactly OPS_PER_TILE DMA ops for `tile` into buffer b.
    // Per-lane clamping keeps every op in-bounds WITHOUT changing the op count
    // (mandatory: the vmcnt immediate assumes 28 ops per tile).
    auto stage = [&](int tile, int b) {
        const long long base = (long long)tile * TILE;
        const float* g = logits + base * NUM_TAGS;
        #pragma unroll
        for (int c = 0; c < LOG_CHUNKS; ++c) {
            const float* p = g + (c << 8) + (lane << 2);
            if (p + 4 > glim) p = glim - 4;           // never triggers for full tiles
            dma16(p, &s_log[b][c << 8]);
        }
        const int* gt = tags + base;
        #pragma unroll
        for (int c = 0; c < TAG_CHUNKS; ++c) {
            const int* p = gt + (c << 6) + lane;
            if (p >= tlim) p = tags;                  // garbage lands in unread slots
            dma4(p, &s_tag[b][c << 6]);
        }
    };

    float acc = 0.0f;
    const int tile0  = blockIdx.x;
    const int stride = gridDim.x;

    if (tile0 < ntiles) {
        stage(tile0, 0);                              // prologue: fill the pipe
        if (tile0 + stride < ntiles) stage(tile0 + stride, 1);

        int b = 0;
        for (int t = tile0; t < ntiles; t += stride, b ^= 1) {
            // Wait for tile t's 28 ops; leave tile t+stride's 28 in flight.
            if (t + stride < ntiles)
                asm volatile("s_waitcnt vmcnt(28)" ::: "memory");
            else
                asm volatile("s_waitcnt vmcnt(0)" ::: "memory");
            __builtin_amdgcn_sched_barrier(0);

            // ---- select: lane handles rows lane and lane+64 ----
            const long long base = (long long)t * TILE;
            const long long rem  = nn - base;
            const int rows = (rem < TILE) ? (int)rem : TILE;
            #pragma unroll
            for (int rh = 0; rh < 2; ++rh) {
                const int r = lane + (rh << 6);
                if (r < rows) {
                    const int tg = s_tag[b][r];
                    float v = s_log[b][r * NUM_TAGS + tg];
                    if (base + r + 1 < nn)            // boundary tag staged at [r+1]<=128
                        v += s_trans[tg * NUM_TAGS + s_tag[b][r + 1]];
                    acc += v;
                }
            }

            // Drain LDS reads before the DMA below can overwrite buffer b.
            asm volatile("s_waitcnt lgkmcnt(0)" ::: "memory");
            __builtin_amdgcn_sched_barrier(0);

            const int tnext = t + 2 * stride;
            if (tnext < ntiles) stage(tnext, b);      // refill this buffer
        }
    }

    // single-wave reduction -> one atomic per block
    #pragma unroll
    for (int off = 32; off > 0; off >>= 1)
        acc += __shfl_down(acc, off, 64);
    if (lane == 0)
        atomicAdd(out, -acc);                         // reference returns -(emit+trans)
}

extern "C" void kernel_launch(void* const* d_in, const int* in_sizes, int n_in,
                              void* d_out, int out_size, void* d_ws, size_t ws_size,
                              hipStream_t stream) {
    const float* logits = (const float*)d_in[0];
    const int*   tags   = (const int*)d_in[1];
    const float* trans  = (const float*)d_in[2];
    float* out = (float*)d_out;
    const int n = in_sizes[1];  // SEQ_LEN

    // d_out is poisoned before every timed launch — zero it on-stream.
    hipMemsetAsync(out, 0, sizeof(float), stream);

    const int ntiles = (n + TILE - 1) / TILE;
    const int grid = (ntiles < GRID) ? ntiles : GRID;  // 62.7 KB LDS -> 2 blocks/CU, all resident
    crf_score_kernel<<<grid, 64, 0, stream>>>(logits, tags, trans, out, n);
}

// Round 6
// 522.655 us; speedup vs baseline: 1.3200x; 1.0024x over previous
//
#include <hip/hip_runtime.h>
#include <stdint.h>

// CRF path score: out = -( sum_i logits[i, tags[i]] + sum_{i>0} T[tags[i-1], tags[i]] )
// S = 2,000,000 rows, NUM_TAGS = 50. Memory-bound: must stream 400 MB of logits.
//
// R6 (third submit; two prior attempts died at container ACQUISITION — no
// timing block in the result JSON => kernel never ran. Pure infra.)
// R5 -> R6: more independent DMA streams. R4/R5 both had only 2 issue-streams
// per CU; each stream's serial per-tile gap (wait -> select -> lgkmcnt ->
// re-issue) left the CU's in-flight bytes sagging below the ~22 KB BW*latency
// product -> ~2.9 TB/s effective. Now: 128-thread blocks, TWO independent
// single-wave pipelines per block (no barriers in the loop), 2 blocks/CU
// -> 4 streams/CU (one per SIMD), TILE=64 rows (12.8 KB), double-buffered,
// counted s_waitcnt vmcnt(16). Gaps of the 4 streams mutually overlap.
// Fast-path (full) tiles skip per-lane clamps via a wave-uniform branch with
// IDENTICAL op count (16) so the vmcnt immediates stay valid on both paths.
// HBM floor: 400 MB logits + 8 MB tags @ ~6.3 TB/s ~= 66 us.

#define NUM_TAGS 50
#define TILE 64                  // rows per wave-tile
#define LOG16 12                 // dma16 chunks: 12 x 1024 B = floats [0, 3072)
#define LOG4  2                  // dma4 chunks: floats [3072, 3200)
#define TAG4  2                  // dma4 chunks: 128 ints staged (need 65)
#define OPS (LOG16 + LOG4 + TAG4)   // 16 vmem ops per tile, ALWAYS
#define THREADS 128
#define WPB 2                    // waves (= independent pipelines) per block
#define GRID 512

typedef __attribute__((address_space(3))) uint32_t lds_u32_t;
typedef __attribute__((address_space(1))) uint32_t g_u32_t;

__device__ __forceinline__ void dma16(const void* gp, void* lds) {
    __builtin_amdgcn_global_load_lds((const g_u32_t*)(uintptr_t)gp,
        (lds_u32_t*)(uint32_t)(uintptr_t)lds, 16, 0, 0);
}
__device__ __forceinline__ void dma4(const void* gp, void* lds) {
    __builtin_amdgcn_global_load_lds((const g_u32_t*)(uintptr_t)gp,
        (lds_u32_t*)(uint32_t)(uintptr_t)lds, 4, 0, 0);
}

__global__ __launch_bounds__(THREADS) void crf_score_kernel(
    const float* __restrict__ logits,
    const int*   __restrict__ tags,
    const float* __restrict__ trans,
    float* __restrict__ out,
    int n)
{
    __shared__ __align__(16) float s_log[WPB][2][TILE * NUM_TAGS];  // 51200 B
    __shared__ __align__(16) int   s_tag[WPB][2][128];              //  2048 B
    __shared__ __align__(16) float s_trans[NUM_TAGS * NUM_TAGS];    // 10000 B
    // total ~63.2 KB -> 2 blocks/CU -> 4 independent wave-pipelines per CU

    const int tid  = threadIdx.x;
    const int lane = tid & 63;
    const int w    = tid >> 6;

    // one-time transitions staging (shared by both waves) — only barrier in kernel
    for (int i = tid; i < (NUM_TAGS * NUM_TAGS) / 4; i += THREADS)
        ((uint4*)s_trans)[i] = ((const uint4*)trans)[i];
    __syncthreads();

    const long long nn = n;
    const int ntiles = (int)((nn + TILE - 1) / TILE);
    const int stream = blockIdx.x * WPB + w;       // this wave's pipeline id
    const int stride = gridDim.x * WPB;            // 1024 streams

    const float* glim = logits + nn * NUM_TAGS;
    const int*   tlim = tags + nn;

    // Issue exactly OPS (=16) DMA ops for `tile` into buffer b.
    auto stage = [&](int tile, int b) {
        const long long base = (long long)tile * TILE;
        const float* g  = logits + base * NUM_TAGS;
        const int*   gt = tags + base;
        if (base + TILE + 64 <= nn) {
            // fast path: everything (incl. the 128-int tag window) in bounds
            #pragma unroll
            for (int c = 0; c < LOG16; ++c)
                dma16(g + (c << 8) + (lane << 2), &s_log[w][b][c << 8]);
            #pragma unroll
            for (int c = 0; c < LOG4; ++c)
                dma4(g + (LOG16 << 8) + (c << 6) + lane,
                     &s_log[w][b][(LOG16 << 8) + (c << 6)]);
            #pragma unroll
            for (int c = 0; c < TAG4; ++c)
                dma4(gt + (c << 6) + lane, &s_tag[w][b][c << 6]);
        } else {
            // clamped path: same 16 ops, per-lane pointer clamps; clamped
            // duplicates land only in slots the select never reads.
            #pragma unroll
            for (int c = 0; c < LOG16; ++c) {
                const float* p = g + (c << 8) + (lane << 2);
                if (p + 4 > glim) p = glim - 4;
                dma16(p, &s_log[w][b][c << 8]);
            }
            #pragma unroll
            for (int c = 0; c < LOG4; ++c) {
                const float* p = g + (LOG16 << 8) + (c << 6) + lane;
                if (p + 1 > glim) p = glim - 1;
                dma4(p, &s_log[w][b][(LOG16 << 8) + (c << 6)]);
            }
            #pragma unroll
            for (int c = 0; c < TAG4; ++c) {
                const int* p = gt + (c << 6) + lane;
                if (p >= tlim) p = tags;
                dma4(p, &s_tag[w][b][c << 6]);
            }
        }
    };

    float acc = 0.0f;
    if (stream < ntiles) {
        stage(stream, 0);                               // fill the pipe
        if (stream + stride < ntiles) stage(stream + stride, 1);

        int b = 0;
        for (int t = stream; t < ntiles; t += stride, b ^= 1) {
            // wait for tile t's 16 ops; keep the next tile's 16 in flight
            if (t + stride < ntiles)
                asm volatile("s_waitcnt vmcnt(16)" ::: "memory");
            else
                asm volatile("s_waitcnt vmcnt(0)" ::: "memory");
            __builtin_amdgcn_sched_barrier(0);

            // ---- select: one row per lane ----
            const long long base = (long long)t * TILE;
            const long long rem  = nn - base;
            const int rows = (rem < TILE) ? (int)rem : TILE;
            if (lane < rows) {
                const int tg = s_tag[w][b][lane];
                float v = s_log[w][b][lane * NUM_TAGS + tg];
                if (base + lane + 1 < nn)               // boundary tag at slot [lane+1]
                    v += s_trans[tg * NUM_TAGS + s_tag[w][b][lane + 1]];
                acc += v;
            }

            // drain LDS reads before re-staging this buffer
            asm volatile("s_waitcnt lgkmcnt(0)" ::: "memory");
            __builtin_amdgcn_sched_barrier(0);

            const int tn = t + 2 * stride;
            if (tn < ntiles) stage(tn, b);
        }
    }

    // wave reduce -> one atomic per wave (1024 total, negligible)
    #pragma unroll
    for (int off = 32; off > 0; off >>= 1)
        acc += __shfl_down(acc, off, 64);
    if (lane == 0)
        atomicAdd(out, -acc);                           // reference returns -(emit+trans)
}

extern "C" void kernel_launch(void* const* d_in, const int* in_sizes, int n_in,
                              void* d_out, int out_size, void* d_ws, size_t ws_size,
                              hipStream_t stream) {
    const float* logits = (const float*)d_in[0];
    const int*   tags   = (const int*)d_in[1];
    const float* trans  = (const float*)d_in[2];
    float* out = (float*)d_out;
    const int n = in_sizes[1];  // SEQ_LEN

    // d_out is poisoned before every timed launch — zero it on-stream.
    hipMemsetAsync(out, 0, sizeof(float), stream);

    const int ntiles = (n + TILE - 1) / TILE;
    const int nstreams_needed = (ntiles + WPB - 1) / WPB;
    const int grid = (nstreams_needed < GRID) ? nstreams_needed : GRID;
    crf_score_kernel<<<grid, THREADS, 0, stream>>>(logits, tags, trans, out, n);
}

// Round 7
// 522.067 us; speedup vs baseline: 1.3215x; 1.0011x over previous
//
#include <hip/hip_runtime.h>
#include <stdint.h>

// CRF path score: out = -( sum_i logits[i, tags[i]] + sum_{i>0} T[tags[i-1], tags[i]] )
// S = 2,000,000 rows, NUM_TAGS = 50. Memory-bound: stream 400 MB of logits.
//
// R6 -> R7: drop global_load_lds entirely. Evidence: three structurally
// different DMA schedules (R4 barrier-convoy, R5 counted-vmcnt 2 streams/CU,
// R6 4 streams/CU) all landed at ~140us =~ 2.9 TB/s -- schedule-invariant =>
// hardware path cap. Theory H1: the LDS-DMA path is ~half-rate vs regular
// vector loads (every 6+ TB/s measurement on this chip -- m13 copy, the 6.5
// TB/s poison fills -- uses the regular path). So: stage with plain uint4
// loads + ds_write, fused per-iteration (max ~4 uint4 live, no R3-style
// scratch spill), and hide latency with OCCUPANCY (m114): 36.3 KB LDS ->
// 4 blocks/CU, 16 waves/CU, phases of different blocks interleave.
// HBM floor: 400 MB logits + 8 MB tags @ ~6.3 TB/s ~= 66 us.

#define NUM_TAGS 50
#define TILE 128                        // rows per block-tile
#define THREADS 256
#define NVEC (TILE * NUM_TAGS / 4)      // 1600 uint4 per tile
#define GRID 1024                       // 4 blocks/CU x 256 CU

__global__ __launch_bounds__(THREADS) void crf_score_kernel(
    const float* __restrict__ logits,
    const int*   __restrict__ tags,
    const float* __restrict__ trans,
    float* __restrict__ out,
    int n)
{
    __shared__ __align__(16) float s_log[TILE * NUM_TAGS];       // 25600 B
    __shared__ __align__(16) float s_trans[NUM_TAGS * NUM_TAGS]; // 10000 B
    __shared__ int   s_tag[TILE + 1];                            //   516 B
    __shared__ float s_part[THREADS / 64];
    // ~36.3 KB -> 4 blocks/CU (LDS-bound), 16 waves/CU

    const int tid  = threadIdx.x;
    const int lane = tid & 63;
    const int wid  = tid >> 6;
    const long long nn = n;

    // one-time transitions staging (read in select, first barrier covers it)
    for (int i = tid; i < (NUM_TAGS * NUM_TAGS) / 4; i += THREADS)
        ((uint4*)s_trans)[i] = ((const uint4*)trans)[i];

    const int ntiles = (int)((nn + TILE - 1) / TILE);
    float acc = 0.0f;

    for (int t = blockIdx.x; t < ntiles; t += gridDim.x) {
        const long long base = (long long)t * TILE;       // row index
        const long long rem  = nn - base;
        const int rows = (rem < TILE) ? (int)rem : TILE;

        // ---- stage: fused load->store, compiler pipelines with its own vmcnt ----
        const uint4* g4 = (const uint4*)(logits + base * NUM_TAGS);  // 25600B-aligned
        const int nv = (rows * NUM_TAGS) >> 2;            // rows always even here
        #pragma unroll 4
        for (int i = tid; i < nv; i += THREADS)
            ((uint4*)s_log)[i] = g4[i];
        if (tid <= rows && base + tid < nn)
            s_tag[tid] = tags[base + tid];                // coalesced, 129 lanes

        __syncthreads();                                  // tile staged

        // ---- select: one row per thread (tid < 128), tiny phase ----
        if (tid < rows) {
            const int tg = s_tag[tid];
            float v = s_log[tid * NUM_TAGS + tg];
            if (base + tid + 1 < nn)                      // boundary into next tile
                v += s_trans[tg * NUM_TAGS + s_tag[tid + 1]];
            acc += v;
        }

        __syncthreads();                                  // protect s_log reuse
    }

    // ---- hierarchical reduce -> one atomic per block ----
    #pragma unroll
    for (int off = 32; off > 0; off >>= 1)
        acc += __shfl_down(acc, off, 64);
    if (lane == 0) s_part[wid] = acc;
    __syncthreads();
    if (wid == 0) {
        float v = (lane < THREADS / 64) ? s_part[lane] : 0.0f;
        #pragma unroll
        for (int off = 2; off > 0; off >>= 1)
            v += __shfl_down(v, off, 64);
        if (lane == 0)
            atomicAdd(out, -v);                           // reference returns -(emit+trans)
    }
}

extern "C" void kernel_launch(void* const* d_in, const int* in_sizes, int n_in,
                              void* d_out, int out_size, void* d_ws, size_t ws_size,
                              hipStream_t stream) {
    const float* logits = (const float*)d_in[0];
    const int*   tags   = (const int*)d_in[1];
    const float* trans  = (const float*)d_in[2];
    float* out = (float*)d_out;
    const int n = in_sizes[1];  // SEQ_LEN

    // d_out is poisoned before every timed launch — zero it on-stream.
    hipMemsetAsync(out, 0, sizeof(float), stream);

    const int ntiles = (n + TILE - 1) / TILE;
    const int grid = (ntiles < GRID) ? ntiles : GRID;
    crf_score_kernel<<<grid, THREADS, 0, stream>>>(logits, tags, trans, out, n);
}